// Round 3
// baseline (733.887 us; speedup 1.0000x reference)
//
#include <hip/hip_runtime.h>
#include <hip/hip_cooperative_groups.h>

namespace cg = cooperative_groups;

constexpr int NN = 100000;   // nodes (= 3125 * 32 exactly)
constexpr int NE = 1600000;  // edges
constexpr int DD = 64;       // channels
constexpr int NG = 256;      // graphs

constexpr int BKT_SHIFT = 8;                   // 256 nodes per bucket
constexpr int NBKT = (NN + 255) >> BKT_SHIFT;  // 391 buckets
constexpr int CAP = 16384;                     // pair window per bucket (mean 4092)
constexpr int NTILE = NN / 32;                 // 3125 gin tiles

// legacy (fallback) build params
constexpr int EPB = 4096;
constexpr int NEB = (NE + EPB - 1) / EPB;  // 391
constexpr int XCONV_TOTAL = NN * 16;       // float4 items for x->bf16 (1.6M)
constexpr int XCONV_HALF_BLKS = XCONV_TOTAL / 256 / 2;

// fused build params
constexpr int FEPB = 2048;                     // smaller: LDS union must fit gin
constexpr int FNEB = (NE + FEPB - 1) / FEPB;   // 782
constexpr int XCB = XCONV_TOTAL / 256;         // 6250 xconv work blocks
constexpr int SMEM_BYTES = NBKT * 8 + FEPB * 4 + FEPB * 2 + 8;  // 15424

using bf16x8 = __attribute__((ext_vector_type(8))) short;
using f32x4 = __attribute__((ext_vector_type(4))) float;

// ---------------------------------------------------------------------------
// bf16 helpers (manual, RNE)
// ---------------------------------------------------------------------------
__device__ __forceinline__ float b2f(unsigned short u) {
    union { unsigned int u; float f; } c;
    c.u = ((unsigned int)u) << 16;
    return c.f;
}
__device__ __forceinline__ unsigned short f2b(float f) {
    union { float f; unsigned int u; } c;
    c.f = f;
    unsigned int u = c.u + 0x7fff + ((c.u >> 16) & 1);
    return (unsigned short)(u >> 16);
}
__device__ __forceinline__ float lo16(unsigned int u) {
    union { unsigned int u; float f; } c;
    c.u = u << 16;
    return c.f;
}
__device__ __forceinline__ float hi16(unsigned int u) {
    union { unsigned int u; float f; } c;
    c.u = u & 0xffff0000u;
    return c.f;
}
__device__ __forceinline__ unsigned int pk(float a, float b) {
    return ((unsigned int)f2b(a)) | (((unsigned int)f2b(b)) << 16);
}

__device__ __forceinline__ void xconv(const float* __restrict__ x,
                                      unsigned short* __restrict__ xb, int i) {
    float4 v = reinterpret_cast<const float4*>(x)[i];
    ushort4 o;
    o.x = f2b(v.x); o.y = f2b(v.y); o.z = f2b(v.z); o.w = f2b(v.w);
    reinterpret_cast<ushort4*>(xb)[i] = o;
}

__device__ __forceinline__ void wconv(const float* __restrict__ w,
                                      unsigned short* __restrict__ o, int tid) {
    for (int i = tid; i < 4096; i += 256) {
        int j = i & 7;
        int quad = (i >> 3) & 3;
        int n = (i >> 5) & 63;
        int kb = i >> 11;
        int k = kb * 32 + quad * 8 + j;
        float wv = w[k * 64 + n];
        unsigned short hi = f2b(wv);
        o[i] = hi;
        o[i + 4096] = f2b(wv - b2f(hi));
    }
}

// ---------------------------------------------------------------------------
// gin tile body (shared by fused + legacy). LDS buffers passed in.
// Gather loop is the round-14 2-deep ping-pong: VGPR 28 -> ~18 waves/CU; TLP
// (not per-lane ILP) hides the random-fetch latency.
// ---------------------------------------------------------------------------
__device__ void gin_tile(int base, const uint4* __restrict__ hb4,
                         const float4* __restrict__ selff,
                         const int* __restrict__ rowptr,
                         const int* __restrict__ csr_src,
                         const unsigned short* __restrict__ wf1,
                         const float* __restrict__ b1,
                         const unsigned short* __restrict__ wf2,
                         const float* __restrict__ b2,
                         unsigned short* __restrict__ houtb, int relu_out,
                         int pool_mode, const int* __restrict__ batch,
                         const float* __restrict__ fcw,
                         float* __restrict__ outp,
                         unsigned short* zl, unsigned short* hlh,
                         unsigned short* hll) {
    int tid = threadIdx.x;
    int lane = tid & 63;
    int wv = tid >> 6;

    // ---- Phase A: gather + self -> zl ----
    {
        int nl = lane >> 3;
        int c = lane & 7;
        int r = wv * 8 + nl;
        int node = base + r;
        int beg = rowptr[node];
        int deg = rowptr[node + 1] - beg;
        float a0 = 0, a1 = 0, a2 = 0, a3 = 0, a4 = 0, a5 = 0, a6 = 0, a7 = 0;
        int nb = (deg + 7) >> 3;
        int idx = (c < deg) ? csr_src[beg + c] : 0;
        int gbase = nl << 3;
        for (int b = 0; b < nb; ++b) {
            int nj = ((b + 1) << 3) + c;
            int nextIdx = (b + 1 < nb && nj < deg) ? csr_src[beg + nj] : 0;
            int cnt = min(8, deg - (b << 3));
            int s0 = __shfl(idx, gbase, 64);
            uint4 v0 = hb4[s0 * 8 + c];
            for (int e = 1; e < cnt; ++e) {
                int s1 = __shfl(idx, gbase + e, 64);
                uint4 v1 = hb4[s1 * 8 + c];  // issue before consuming v0
                a0 += lo16(v0.x); a1 += hi16(v0.x);
                a2 += lo16(v0.y); a3 += hi16(v0.y);
                a4 += lo16(v0.z); a5 += hi16(v0.z);
                a6 += lo16(v0.w); a7 += hi16(v0.w);
                v0 = v1;
            }
            a0 += lo16(v0.x); a1 += hi16(v0.x);
            a2 += lo16(v0.y); a3 += hi16(v0.y);
            a4 += lo16(v0.z); a5 += hi16(v0.z);
            a6 += lo16(v0.w); a7 += hi16(v0.w);
            idx = nextIdx;
        }
        if (selff) {
            float4 s0 = selff[(size_t)node * 16 + 2 * c];
            float4 s1 = selff[(size_t)node * 16 + 2 * c + 1];
            a0 += s0.x; a1 += s0.y; a2 += s0.z; a3 += s0.w;
            a4 += s1.x; a5 += s1.y; a6 += s1.z; a7 += s1.w;
        } else {
            uint4 sv = hb4[node * 8 + c];
            a0 += lo16(sv.x); a1 += hi16(sv.x);
            a2 += lo16(sv.y); a3 += hi16(sv.y);
            a4 += lo16(sv.z); a5 += hi16(sv.z);
            a6 += lo16(sv.w); a7 += hi16(sv.w);
        }
        uint4 o;
        o.x = pk(a0, a1); o.y = pk(a2, a3); o.z = pk(a4, a5); o.w = pk(a6, a7);
        *reinterpret_cast<uint4*>(&zl[r * 72 + c * 8]) = o;
    }
    __syncthreads();

    // ---- Phase B: MLP ----
    int m = lane & 15;
    int quad = lane >> 4;
    int mt = wv >> 1;
    int nh = wv & 1;
    int lrow = mt * 16 + m;

    bf16x8 a0 = *reinterpret_cast<const bf16x8*>(&zl[lrow * 72 + quad * 8]);
    bf16x8 a1 = *reinterpret_cast<const bf16x8*>(&zl[lrow * 72 + 32 + quad * 8]);
    const bf16x8* wh1 = reinterpret_cast<const bf16x8*>(wf1);
    const bf16x8* wl1 = reinterpret_cast<const bf16x8*>(wf1 + 4096);
    f32x4 acc[2];
#pragma unroll
    for (int nt2 = 0; nt2 < 2; ++nt2) {
        int n = (nh * 2 + nt2) * 16 + m;
        bf16x8 bh0 = wh1[(0 * 64 + n) * 4 + quad];
        bf16x8 bh1 = wh1[(1 * 64 + n) * 4 + quad];
        bf16x8 bl0 = wl1[(0 * 64 + n) * 4 + quad];
        bf16x8 bl1 = wl1[(1 * 64 + n) * 4 + quad];
        f32x4 c = {0.f, 0.f, 0.f, 0.f};
        c = __builtin_amdgcn_mfma_f32_16x16x32_bf16(a0, bh0, c, 0, 0, 0);
        c = __builtin_amdgcn_mfma_f32_16x16x32_bf16(a1, bh1, c, 0, 0, 0);
        c = __builtin_amdgcn_mfma_f32_16x16x32_bf16(a0, bl0, c, 0, 0, 0);
        c = __builtin_amdgcn_mfma_f32_16x16x32_bf16(a1, bl1, c, 0, 0, 0);
        acc[nt2] = c;
    }
#pragma unroll
    for (int nt2 = 0; nt2 < 2; ++nt2) {
        int col = (nh * 2 + nt2) * 16 + m;
        float bb = b1[col];
#pragma unroll
        for (int rr = 0; rr < 4; ++rr) {
            float v = fmaxf(acc[nt2][rr] + bb, 0.f);
            unsigned short hi = f2b(v);
            hlh[(mt * 16 + quad * 4 + rr) * 72 + col] = hi;
            hll[(mt * 16 + quad * 4 + rr) * 72 + col] = f2b(v - b2f(hi));
        }
    }
    __syncthreads();

    bf16x8 ch0 = *reinterpret_cast<const bf16x8*>(&hlh[lrow * 72 + quad * 8]);
    bf16x8 ch1 = *reinterpret_cast<const bf16x8*>(&hlh[lrow * 72 + 32 + quad * 8]);
    bf16x8 cl0 = *reinterpret_cast<const bf16x8*>(&hll[lrow * 72 + quad * 8]);
    bf16x8 cl1 = *reinterpret_cast<const bf16x8*>(&hll[lrow * 72 + 32 + quad * 8]);
    const bf16x8* wh2 = reinterpret_cast<const bf16x8*>(wf2);
    const bf16x8* wl2 = reinterpret_cast<const bf16x8*>(wf2 + 4096);
#pragma unroll
    for (int nt2 = 0; nt2 < 2; ++nt2) {
        int n = (nh * 2 + nt2) * 16 + m;
        bf16x8 bh0 = wh2[(0 * 64 + n) * 4 + quad];
        bf16x8 bh1 = wh2[(1 * 64 + n) * 4 + quad];
        bf16x8 bl0 = wl2[(0 * 64 + n) * 4 + quad];
        bf16x8 bl1 = wl2[(1 * 64 + n) * 4 + quad];
        f32x4 c = {0.f, 0.f, 0.f, 0.f};
        c = __builtin_amdgcn_mfma_f32_16x16x32_bf16(ch0, bh0, c, 0, 0, 0);
        c = __builtin_amdgcn_mfma_f32_16x16x32_bf16(ch1, bh1, c, 0, 0, 0);
        c = __builtin_amdgcn_mfma_f32_16x16x32_bf16(ch0, bl0, c, 0, 0, 0);
        c = __builtin_amdgcn_mfma_f32_16x16x32_bf16(ch1, bl1, c, 0, 0, 0);
        c = __builtin_amdgcn_mfma_f32_16x16x32_bf16(cl0, bh0, c, 0, 0, 0);
        c = __builtin_amdgcn_mfma_f32_16x16x32_bf16(cl1, bh1, c, 0, 0, 0);
        acc[nt2] = c;
    }
    __syncthreads();

    if (pool_mode) {
        float psum[4] = {0.f, 0.f, 0.f, 0.f};
#pragma unroll
        for (int nt2 = 0; nt2 < 2; ++nt2) {
            int col = (nh * 2 + nt2) * 16 + m;
            float fw = fcw[col];
            float bb = b2[col];
#pragma unroll
            for (int rr = 0; rr < 4; ++rr) psum[rr] += (acc[nt2][rr] + bb) * fw;
        }
#pragma unroll
        for (int rr = 0; rr < 4; ++rr)
#pragma unroll
            for (int off = 8; off > 0; off >>= 1)
                psum[rr] += __shfl_down(psum[rr], off, 64);
        float* gsum = reinterpret_cast<float*>(hlh);
        gsum[tid] = 0.f;
        __syncthreads();
        if (m == 0) {
#pragma unroll
            for (int rr = 0; rr < 4; ++rr) {
                int row = base + mt * 16 + quad * 4 + rr;
                atomicAdd(&gsum[batch[row]], psum[rr]);
            }
        }
        __syncthreads();
        float v = gsum[tid];
        if (v != 0.f) unsafeAtomicAdd(&outp[tid], v);
        return;
    }

#pragma unroll
    for (int nt2 = 0; nt2 < 2; ++nt2) {
        int col = (nh * 2 + nt2) * 16 + m;
        float bb = b2[col];
#pragma unroll
        for (int rr = 0; rr < 4; ++rr) {
            float v = acc[nt2][rr] + bb;
            if (relu_out) v = fmaxf(v, 0.f);
            hlh[(mt * 16 + quad * 4 + rr) * 72 + col] = f2b(v);
        }
    }
    __syncthreads();
    {
        int row = tid >> 3;
        int ch = tid & 7;
        uint4 v = *reinterpret_cast<const uint4*>(&hlh[row * 72 + ch * 8]);
        *reinterpret_cast<uint4*>(houtb + (size_t)(base + row) * 64 + ch * 8) = v;
    }
}

// ---------------------------------------------------------------------------
// Fused whole-model cooperative kernel. Phases separated by grid.sync():
//   P0 init | P1 pscat(+xconv) | P2 bfill | P3 L0 | P4 L1 | P5 L2+pool
// One dispatch replaces six -> removes ~5x inter-dispatch overhead.
// ---------------------------------------------------------------------------
struct Prm {
    const float* x;
    const int* ei;
    const int* batch;
    const float* w1f[3];
    const float* b1v[3];
    const float* w2f[3];
    const float* b2v[3];
    const float* fcw;
    const float* fcb;
    float* out;
    int* pairs;
    unsigned short* H0;
    unsigned short* H1;
    int* rowptr;
    int* csr;
    int* gcnt;
    unsigned short* wf;
};

__global__ __launch_bounds__(256) void fused_k(Prm p) {
    cg::grid_group grid = cg::this_grid();
    __shared__ __align__(16) char smem[SMEM_BYTES];
    int tid = threadIdx.x;
    int bid = blockIdx.x;
    int nbk = gridDim.x;

    // ---- P0: weights -> split bf16; out init; gcnt zero ----
    if (bid < 6) {
        const float* ws[6] = {p.w1f[0], p.w2f[0], p.w1f[1],
                              p.w2f[1], p.w1f[2], p.w2f[2]};
        wconv(ws[bid], p.wf + bid * 8192, tid);
    } else if (bid == 6) {
        if (tid < NG) p.out[tid] = p.fcb[0];
        for (int i = tid; i < NBKT; i += 256) p.gcnt[i] = 0;
    }
    grid.sync();

    // ---- P1: pscat chunks (w < FNEB) + xconv blocks (w >= FNEB) ----
    {
        int* lc = (int*)smem;
        int* gb = lc + NBKT;
        int* pe = gb + NBKT;
        unsigned short* pb = (unsigned short*)(pe + FEPB);
        for (int w = bid; w < FNEB + XCB; w += nbk) {
            if (w < FNEB) {
                for (int i = tid; i < NBKT; i += 256) lc[i] = 0;
                __syncthreads();
                int base = w * FEPB;
                int n = min(base + FEPB, NE) - base;
                for (int t = tid; t < n; t += 256) {
                    int src = p.ei[base + t];
                    int dst = p.ei[NE + base + t];
                    int b = dst >> BKT_SHIFT;
                    pe[t] = src | ((dst & 255) << 17);
                    pb[t] = (unsigned short)b;
                    atomicAdd(&lc[b], 1);
                }
                __syncthreads();
                for (int i = tid; i < NBKT; i += 256) {
                    int c = lc[i];
                    gb[i] = c ? atomicAdd(&p.gcnt[i], c) : 0;
                }
                __syncthreads();
                for (int i = tid; i < NBKT; i += 256) lc[i] = 0;
                __syncthreads();
                for (int t = tid; t < n; t += 256) {
                    int b = pb[t];
                    int pos = gb[b] + atomicAdd(&lc[b], 1);
                    if (pos < CAP) p.pairs[(size_t)b * CAP + pos] = pe[t];
                }
                __syncthreads();
            } else {
                int i = (w - FNEB) * 256 + tid;
                xconv(p.x, p.H0, i);
            }
        }
    }
    grid.sync();

    // ---- P2: bfill (buckets grid-strided) ----
    {
        int* ldeg = (int*)smem;
        int* sh = ldeg + 256;
        int* lcur = sh + 256;
        int* redsh = lcur + 256;
        for (int b = bid; b < NBKT; b += nbk) {
            int t = tid;
            int part = 0;
            for (int i = t; i < NBKT; i += 256)
                if (i < b) part += min(p.gcnt[i], CAP);
#pragma unroll
            for (int off = 32; off > 0; off >>= 1)
                part += __shfl_down(part, off, 64);
            if ((t & 63) == 0) redsh[t >> 6] = part;
            ldeg[t] = 0;
            __syncthreads();
            int cbeg = redsh[0] + redsh[1] + redsh[2] + redsh[3];
            int pcnt = min(p.gcnt[b], CAP);
            const int* pw = p.pairs + (size_t)b * CAP;
            for (int i = t; i < pcnt; i += 256)
                atomicAdd(&ldeg[(pw[i] >> 17) & 255], 1);
            __syncthreads();
            int v = ldeg[t];
            sh[t] = v;
            __syncthreads();
            for (int off = 1; off < 256; off <<= 1) {
                int u = (t >= off) ? sh[t - off] : 0;
                __syncthreads();
                sh[t] += u;
                __syncthreads();
            }
            int lexcl = sh[t] - v;
            int node = (b << BKT_SHIFT) + t;
            if (node < NN) {
                p.rowptr[node] = cbeg + lexcl;
                if (node == NN - 1) p.rowptr[NN] = cbeg + lexcl + v;
            }
            lcur[t] = lexcl;
            __syncthreads();
            for (int i = t; i < pcnt; i += 256) {
                int pr = pw[i];
                int pos = atomicAdd(&lcur[(pr >> 17) & 255], 1);
                p.csr[cbeg + pos] = pr & 0x1FFFF;
            }
            __syncthreads();
        }
    }
    grid.sync();

    // ---- P3..P5: GIN layers ----
    unsigned short* zl = (unsigned short*)smem;
    unsigned short* hlh = zl + 2304;
    unsigned short* hll = hlh + 2304;

    for (int tile = bid; tile < NTILE; tile += nbk)
        gin_tile(tile * 32, (const uint4*)p.H0, (const float4*)p.x, p.rowptr,
                 p.csr, p.wf + 0 * 8192, p.b1v[0], p.wf + 1 * 8192, p.b2v[0],
                 p.H1, 1, 0, nullptr, nullptr, nullptr, zl, hlh, hll);
    grid.sync();

    for (int tile = bid; tile < NTILE; tile += nbk)
        gin_tile(tile * 32, (const uint4*)p.H1, nullptr, p.rowptr, p.csr,
                 p.wf + 2 * 8192, p.b1v[1], p.wf + 3 * 8192, p.b2v[1], p.H0, 1,
                 0, nullptr, nullptr, nullptr, zl, hlh, hll);
    grid.sync();

    for (int tile = bid; tile < NTILE; tile += nbk)
        gin_tile(tile * 32, (const uint4*)p.H0, nullptr, p.rowptr, p.csr,
                 p.wf + 4 * 8192, p.b1v[2], p.wf + 5 * 8192, p.b2v[2], nullptr,
                 0, 1, p.batch, p.fcw, p.out, zl, hlh, hll);
}

// ---------------------------------------------------------------------------
// Legacy fallback path (proven round-2 kernels), used if cooperative launch
// is rejected (e.g. unsupported under graph capture).
// ---------------------------------------------------------------------------
__global__ __launch_bounds__(256) void init_k(const float* __restrict__ w0,
                                              const float* __restrict__ w1,
                                              const float* __restrict__ w2,
                                              const float* __restrict__ w3,
                                              const float* __restrict__ w4,
                                              const float* __restrict__ w5,
                                              unsigned short* __restrict__ wf,
                                              int* __restrict__ gcnt,
                                              const float* __restrict__ fcb,
                                              float* __restrict__ outp) {
    int bid = blockIdx.x;
    int tid = threadIdx.x;
    if (bid < 6) {
        const float* ws[6] = {w0, w1, w2, w3, w4, w5};
        wconv(ws[bid], wf + bid * 8192, tid);
    } else {
        if (tid < NG) outp[tid] = fcb[0];
        for (int i = tid; i < NBKT; i += 256) gcnt[i] = 0;
    }
}

__global__ __launch_bounds__(256) void pscat_k(const int* __restrict__ ei,
                                               int* __restrict__ gcnt,
                                               int* __restrict__ pairs,
                                               const float* __restrict__ x,
                                               unsigned short* __restrict__ xb) {
    if (blockIdx.x >= NEB) {
        int i = (blockIdx.x - NEB) * 256 + threadIdx.x;
        xconv(x, xb, i);
        return;
    }
    __shared__ int lc[NBKT];
    __shared__ int gb[NBKT];
    __shared__ int pe[EPB];
    __shared__ unsigned short pb[EPB];
    int tid = threadIdx.x;
    for (int i = tid; i < NBKT; i += 256) lc[i] = 0;
    __syncthreads();
    int base = blockIdx.x * EPB;
    int n = min(base + EPB, NE) - base;
    for (int t = tid; t < n; t += 256) {
        int src = ei[base + t];
        int dst = ei[NE + base + t];
        int b = dst >> BKT_SHIFT;
        pe[t] = src | ((dst & 255) << 17);
        pb[t] = (unsigned short)b;
        atomicAdd(&lc[b], 1);
    }
    __syncthreads();
    for (int i = tid; i < NBKT; i += 256) {
        int c = lc[i];
        gb[i] = c ? atomicAdd(&gcnt[i], c) : 0;
    }
    __syncthreads();
    for (int i = tid; i < NBKT; i += 256) lc[i] = 0;
    __syncthreads();
    for (int t = tid; t < n; t += 256) {
        int b = pb[t];
        int pos = gb[b] + atomicAdd(&lc[b], 1);
        if (pos < CAP) pairs[(size_t)b * CAP + pos] = pe[t];
    }
}

__global__ __launch_bounds__(256) void bfill_k(const int* __restrict__ pairs,
                                               const int* __restrict__ gcnt,
                                               int* __restrict__ rowptr,
                                               int* __restrict__ csr_src,
                                               const float* __restrict__ x,
                                               unsigned short* __restrict__ xb) {
    if (blockIdx.x >= NBKT) {
        int i = XCONV_TOTAL / 2 + (blockIdx.x - NBKT) * 256 + threadIdx.x;
        xconv(x, xb, i);
        return;
    }
    __shared__ int ldeg[256];
    __shared__ int sh[256];
    __shared__ int lcur[256];
    __shared__ int redsh[4];
    int b = blockIdx.x;
    int t = threadIdx.x;
    int part = 0;
    for (int i = t; i < NBKT; i += 256)
        if (i < b) part += min(gcnt[i], CAP);
#pragma unroll
    for (int off = 32; off > 0; off >>= 1) part += __shfl_down(part, off, 64);
    if ((t & 63) == 0) redsh[t >> 6] = part;
    ldeg[t] = 0;
    __syncthreads();
    int cbeg = redsh[0] + redsh[1] + redsh[2] + redsh[3];
    int pcnt = min(gcnt[b], CAP);
    const int* pw = pairs + (size_t)b * CAP;
    for (int i = t; i < pcnt; i += 256)
        atomicAdd(&ldeg[(pw[i] >> 17) & 255], 1);
    __syncthreads();
    int v = ldeg[t];
    sh[t] = v;
    __syncthreads();
    for (int off = 1; off < 256; off <<= 1) {
        int u = (t >= off) ? sh[t - off] : 0;
        __syncthreads();
        sh[t] += u;
        __syncthreads();
    }
    int lexcl = sh[t] - v;
    int node = (b << BKT_SHIFT) + t;
    if (node < NN) {
        rowptr[node] = cbeg + lexcl;
        if (node == NN - 1) rowptr[NN] = cbeg + lexcl + v;
    }
    lcur[t] = lexcl;
    __syncthreads();
    for (int i = t; i < pcnt; i += 256) {
        int p = pw[i];
        int pos = atomicAdd(&lcur[(p >> 17) & 255], 1);
        csr_src[cbeg + pos] = p & 0x1FFFF;
    }
}

__global__ __launch_bounds__(256) void gin_k(
    const uint4* __restrict__ hb4, const float4* __restrict__ selff,
    const int* __restrict__ rowptr, const int* __restrict__ csr_src,
    const unsigned short* __restrict__ wf1, const float* __restrict__ b1,
    const unsigned short* __restrict__ wf2, const float* __restrict__ b2,
    unsigned short* __restrict__ houtb, int relu_out, int pool_mode,
    const int* __restrict__ batch, const float* __restrict__ fcw,
    float* __restrict__ outp) {
    __shared__ unsigned short zl[32 * 72];
    __shared__ unsigned short hlh[32 * 72];
    __shared__ unsigned short hll[32 * 72];
    gin_tile(blockIdx.x * 32, hb4, selff, rowptr, csr_src, wf1, b1, wf2, b2,
             houtb, relu_out, pool_mode, batch, fcw, outp, zl, hlh, hll);
}

extern "C" void kernel_launch(void* const* d_in, const int* in_sizes, int n_in,
                              void* d_out, int out_size, void* d_ws, size_t ws_size,
                              hipStream_t stream) {
    const float* x = (const float*)d_in[0];
    const int* ei = (const int*)d_in[1];
    const int* batch = (const int*)d_in[2];
    const float* w[3][4];
    for (int l = 0; l < 3; ++l)
        for (int i = 0; i < 4; ++i) w[l][i] = (const float*)d_in[3 + l * 4 + i];
    const float* fcw = (const float*)d_in[15];
    const float* fcb = (const float*)d_in[16];
    float* out = (float*)d_out;

    // workspace layout (~58 MB)
    int* pairs = (int*)d_ws;                               // NBKT*CAP ints
    unsigned short* H1 = (unsigned short*)d_ws;            // aliases pairs
    unsigned short* H0 = (unsigned short*)((char*)d_ws + (size_t)NBKT * CAP * 4);
    int* rowptr = (int*)(H0 + (size_t)NN * DD);
    int* csr_src = rowptr + NN + 1;
    int* gcnt = csr_src + NE;
    unsigned short* wf = (unsigned short*)(gcnt + NBKT);

    static int gridN = -2;  // -2 = not probed
    if (gridN == -2) {
        int maxb = 0;
        if (hipOccupancyMaxActiveBlocksPerMultiprocessor(
                &maxb, reinterpret_cast<const void*>(&fused_k), 256, 0) !=
                hipSuccess ||
            maxb < 1)
            maxb = 0;
        gridN = maxb * 256;  // 256 CUs on MI355X
        if (gridN > NTILE) gridN = NTILE;
    }

    bool done = false;
    if (gridN >= NBKT) {
        Prm prm;
        prm.x = x; prm.ei = ei; prm.batch = batch;
        for (int l = 0; l < 3; ++l) {
            prm.w1f[l] = w[l][0]; prm.b1v[l] = w[l][1];
            prm.w2f[l] = w[l][2]; prm.b2v[l] = w[l][3];
        }
        prm.fcw = fcw; prm.fcb = fcb; prm.out = out;
        prm.pairs = pairs; prm.H0 = H0; prm.H1 = H1;
        prm.rowptr = rowptr; prm.csr = csr_src; prm.gcnt = gcnt; prm.wf = wf;
        void* kp[] = {&prm};
        hipError_t e = hipLaunchCooperativeKernel(
            reinterpret_cast<const void*>(&fused_k), dim3(gridN), dim3(256), kp,
            0, stream);
        if (e == hipSuccess) {
            done = true;
        } else {
            (void)hipGetLastError();  // clear, fall back
        }
    }

    if (!done) {
        init_k<<<7, 256, 0, stream>>>(w[0][0], w[0][2], w[1][0], w[1][2],
                                      w[2][0], w[2][2], wf, gcnt, fcb, out);
        pscat_k<<<NEB + XCONV_HALF_BLKS, 256, 0, stream>>>(ei, gcnt, pairs, x, H0);
        bfill_k<<<NBKT + XCONV_HALF_BLKS, 256, 0, stream>>>(pairs, gcnt, rowptr,
                                                            csr_src, x, H0);
        dim3 lgrid(NTILE);
        gin_k<<<lgrid, 256, 0, stream>>>((const uint4*)H0, (const float4*)x,
                                         rowptr, csr_src, wf + 0 * 8192, w[0][1],
                                         wf + 1 * 8192, w[0][3], H1, 1, 0,
                                         nullptr, nullptr, nullptr);
        gin_k<<<lgrid, 256, 0, stream>>>((const uint4*)H1, nullptr, rowptr,
                                         csr_src, wf + 2 * 8192, w[1][1],
                                         wf + 3 * 8192, w[1][3], H0, 1, 0,
                                         nullptr, nullptr, nullptr);
        gin_k<<<lgrid, 256, 0, stream>>>((const uint4*)H0, nullptr, rowptr,
                                         csr_src, wf + 4 * 8192, w[2][1],
                                         wf + 5 * 8192, w[2][3], nullptr, 0, 1,
                                         batch, fcw, out);
    }
}

// Round 5
// 275.505 us; speedup vs baseline: 2.6638x; 2.6638x over previous
//
#include <hip/hip_runtime.h>

constexpr int NN = 100000;   // nodes (= 3125 * 32 exactly)
constexpr int NE = 1600000;  // edges
constexpr int DD = 64;       // channels
constexpr int NG = 256;      // graphs

constexpr int BKT_SHIFT = 8;                   // 256 nodes per bucket
constexpr int NBKT = (NN + 255) >> BKT_SHIFT;  // 391 buckets
constexpr int EPB = 4096;                      // edges per pscat chunk
constexpr int NEB = (NE + EPB - 1) / EPB;      // 391 chunks
constexpr int CAP = 6144;                      // per-bucket csr window (mean 4096, +32 sigma)
constexpr int XCB = NN * 16 / 256;             // 6250 xconv work blocks

using bf16x8 = __attribute__((ext_vector_type(8))) short;
using f32x4 = __attribute__((ext_vector_type(4))) float;

// ---------------------------------------------------------------------------
// bf16 helpers (manual, RNE)
// ---------------------------------------------------------------------------
__device__ __forceinline__ float b2f(unsigned short u) {
    union { unsigned int u; float f; } c;
    c.u = ((unsigned int)u) << 16;
    return c.f;
}
__device__ __forceinline__ unsigned short f2b(float f) {
    union { float f; unsigned int u; } c;
    c.f = f;
    unsigned int u = c.u + 0x7fff + ((c.u >> 16) & 1);
    return (unsigned short)(u >> 16);
}
__device__ __forceinline__ float lo16(unsigned int u) {
    union { unsigned int u; float f; } c;
    c.u = u << 16;
    return c.f;
}
__device__ __forceinline__ float hi16(unsigned int u) {
    union { unsigned int u; float f; } c;
    c.u = u & 0xffff0000u;
    return c.f;
}
__device__ __forceinline__ unsigned int pk(float a, float b) {
    return ((unsigned int)f2b(a)) | (((unsigned int)f2b(b)) << 16);
}

__device__ __forceinline__ void xconv(const float* __restrict__ x,
                                      unsigned short* __restrict__ xb, int i) {
    float4 v = reinterpret_cast<const float4*>(x)[i];
    ushort4 o;
    o.x = f2b(v.x); o.y = f2b(v.y); o.z = f2b(v.z); o.w = f2b(v.w);
    reinterpret_cast<ushort4*>(xb)[i] = o;
}

__device__ __forceinline__ void wconv(const float* __restrict__ w,
                                      unsigned short* __restrict__ o, int tid) {
    for (int i = tid; i < 4096; i += 256) {
        int j = i & 7;
        int quad = (i >> 3) & 3;
        int n = (i >> 5) & 63;
        int kb = i >> 11;
        int k = kb * 32 + quad * 8 + j;
        float wv = w[k * 64 + n];
        unsigned short hi = f2b(wv);
        o[i] = hi;
        o[i + 4096] = f2b(wv - b2f(hi));
    }
}

// exclusive scan of v across 256 threads (all threads must call); total = incl[255]
__device__ __forceinline__ int scan256_excl(int v, int* sh, int tid, int& total) {
    __syncthreads();
    sh[tid] = v;
    __syncthreads();
    for (int off = 1; off < 256; off <<= 1) {
        int u = (tid >= off) ? sh[tid - off] : 0;
        __syncthreads();
        sh[tid] += u;
        __syncthreads();
    }
    total = sh[255];
    return sh[tid] - v;
}

// ---------------------------------------------------------------------------
// build1_k: everything with no intra-grid dependencies, one dispatch.
//   bid < NEB        : pscat chunk — LDS counting-sort 4096 edges by bucket,
//                      WRITE ocnt[j][b] = (chunk_off<<16)|count (no global
//                      atomics -> no gcnt, no init dependency)
//   bid < NEB+6      : weight -> split bf16 frags
//   bid == NEB+6     : out[g] = fcb
//   else             : x fp32 -> bf16 backfill
// [round-1 lesson: 1.6M per-node global atomics = 143 us; keep LDS-aggregated]
// [round-3 lesson: cooperative grid.sync = 3x regression on gfx950; never]
// [round-4 lesson: barrier REQUIRED between LDS atomic count loop and scan
//  reads — missing one cost a correctness failure (absmax 144).]
// ---------------------------------------------------------------------------
__global__ __launch_bounds__(256) void build1_k(
    const int* __restrict__ ei, int* __restrict__ pairs, int* __restrict__ ocnt,
    const float* __restrict__ x, unsigned short* __restrict__ xb,
    const float* __restrict__ w0, const float* __restrict__ w1,
    const float* __restrict__ w2, const float* __restrict__ w3,
    const float* __restrict__ w4, const float* __restrict__ w5,
    unsigned short* __restrict__ wf, const float* __restrict__ fcb,
    float* __restrict__ outp) {
    int bid = blockIdx.x;
    int tid = threadIdx.x;
    if (bid >= NEB) {
        int r = bid - NEB;
        if (r < 6) {
            const float* ws[6] = {w0, w1, w2, w3, w4, w5};
            wconv(ws[r], wf + r * 8192, tid);
        } else if (r == 6) {
            if (tid < NG) outp[tid] = fcb[0];
        } else {
            xconv(x, xb, (r - 7) * 256 + tid);
        }
        return;
    }
    __shared__ int cntl[NBKT];
    __shared__ int loff[NBKT];
    __shared__ int lcur[NBKT];
    __shared__ int sh[256];
    int j = bid;
    int base = j * EPB;
    int n = min(base + EPB, NE) - base;
    for (int i = tid; i < NBKT; i += 256) cntl[i] = 0;
    __syncthreads();
    for (int t = tid; t < n; t += 256) {
        int dst = ei[NE + base + t];
        atomicAdd(&cntl[dst >> BKT_SHIFT], 1);
    }
    __syncthreads();  // ALL counts visible before scan reads (round-4 bug fix)
    // scan 391 counts: thread t owns elements 2t, 2t+1
    int e0 = 2 * tid, e1 = 2 * tid + 1;
    int c0 = (e0 < NBKT) ? cntl[e0] : 0;
    int c1 = (e1 < NBKT) ? cntl[e1] : 0;
    int tot;
    int ex = scan256_excl(c0 + c1, sh, tid, tot);
    if (e0 < NBKT) loff[e0] = ex;
    if (e1 < NBKT) loff[e1] = ex + c0;
    __syncthreads();
    for (int i = tid; i < NBKT; i += 256) {
        ocnt[j * NBKT + i] = (loff[i] << 16) | cntl[i];
        lcur[i] = 0;
    }
    __syncthreads();
    for (int t = tid; t < n; t += 256) {  // edges re-read: L2-hot (32 KB/chunk)
        int src = ei[base + t];
        int dst = ei[NE + base + t];
        int b = dst >> BKT_SHIFT;
        int pos = loff[b] + atomicAdd(&lcur[b], 1);
        pairs[j * EPB + pos] = src | ((dst & 255) << 17);
    }
}

// ---------------------------------------------------------------------------
// build2_k: bucket b gathers its runs from all chunks (LDS staged), counting-
// sorts by node into its fixed csr window. rowptr/degs per node; no global
// prefix across buckets needed (fixed windows).
// ---------------------------------------------------------------------------
__global__ __launch_bounds__(256) void build2_k(
    const int* __restrict__ pairs, const int* __restrict__ ocnt,
    int* __restrict__ rowptr, int* __restrict__ degs, int* __restrict__ csr) {
    __shared__ int stag[CAP];
    __shared__ int pb_[NBKT];  // dest base per chunk
    __shared__ int po_[NBKT];  // chunk-local run offset
    __shared__ int pc_[NBKT];  // run count per chunk
    __shared__ int sh[256];
    __shared__ int ldeg[256];
    __shared__ int lcur[256];
    int b = blockIdx.x;
    int tid = threadIdx.x;
    int e0 = 2 * tid, e1 = 2 * tid + 1;
    int o0 = 0, c0 = 0, o1 = 0, c1 = 0;
    if (e0 < NBKT) { int v = ocnt[e0 * NBKT + b]; o0 = v >> 16; c0 = v & 0xffff; }
    if (e1 < NBKT) { int v = ocnt[e1 * NBKT + b]; o1 = v >> 16; c1 = v & 0xffff; }
    int tot;
    int ex = scan256_excl(c0 + c1, sh, tid, tot);
    if (e0 < NBKT) { pb_[e0] = ex; po_[e0] = o0; pc_[e0] = c0; }
    if (e1 < NBKT) { pb_[e1] = ex + c0; po_[e1] = o1; pc_[e1] = c1; }
    ldeg[tid] = 0;
    __syncthreads();
    int pcnt = min(tot, CAP);
    // stage runs into LDS packed
    for (int j = tid; j < NBKT; j += 256) {
        int d = pb_[j], pc = pc_[j];
        const int* src = pairs + j * EPB + po_[j];
        for (int k = 0; k < pc; ++k) {
            int dd = d + k;
            if (dd < CAP) stag[dd] = src[k];
        }
    }
    __syncthreads();
    for (int i = tid; i < pcnt; i += 256)
        atomicAdd(&ldeg[(stag[i] >> 17) & 255], 1);
    __syncthreads();
    int v = ldeg[tid];
    int tot2;
    int lexcl = scan256_excl(v, sh, tid, tot2);
    int node = (b << BKT_SHIFT) + tid;
    if (node < NN) {
        rowptr[node] = b * CAP + lexcl;
        degs[node] = v;
    }
    lcur[tid] = lexcl;
    __syncthreads();
    for (int i = tid; i < pcnt; i += 256) {
        int p = stag[i];
        int pos = atomicAdd(&lcur[(p >> 17) & 255], 1);
        csr[b * CAP + pos] = p & 0x1FFFF;
    }
}

// ---------------------------------------------------------------------------
// Fused GIN layer (proven round-2 body; only change: deg from degs[]).
// Gather loop is the round-14 2-deep ping-pong: VGPR 28 -> ~18 waves/CU; TLP
// (not per-lane ILP) hides the random-fetch latency [round-15 evidence:
// depth-8 raised VGPR to 48, dropped occupancy 58->40%, regressed 46->51.5].
// ---------------------------------------------------------------------------
__global__ __launch_bounds__(256) void gin_k(
    const uint4* __restrict__ hb4,     // prev h (bf16): gather + self source
    const float4* __restrict__ selff,  // fp32 self (layer 0) or null
    const int* __restrict__ rowptr, const int* __restrict__ degv,
    const int* __restrict__ csr_src,
    const unsigned short* __restrict__ wf1, const float* __restrict__ b1,
    const unsigned short* __restrict__ wf2, const float* __restrict__ b2,
    unsigned short* __restrict__ houtb, int relu_out, int pool_mode,
    const int* __restrict__ batch, const float* __restrict__ fcw,
    float* __restrict__ outp) {
    __shared__ unsigned short zl[32 * 72];   // z tile (bf16)
    __shared__ unsigned short hlh[32 * 72];  // h1 hi
    __shared__ unsigned short hll[32 * 72];  // h1 lo
    int tid = threadIdx.x;
    int lane = tid & 63;
    int wv = tid >> 6;
    int base = blockIdx.x * 32;

    // ---- Phase A: gather + self -> zl (NN == 3125*32, all nodes valid) ----
    {
        int nl = lane >> 3;  // node slot within wave (0..7)
        int c = lane & 7;    // 16 B chunk within row (0..7)
        int r = wv * 8 + nl; // local row 0..31
        int node = base + r;
        int beg = rowptr[node];
        int deg = degv[node];
        float a0 = 0, a1 = 0, a2 = 0, a3 = 0, a4 = 0, a5 = 0, a6 = 0, a7 = 0;
        int nb = (deg + 7) >> 3;
        int idx = (c < deg) ? csr_src[beg + c] : 0;
        int gbase = nl << 3;
        for (int b = 0; b < nb; ++b) {
            int nj = ((b + 1) << 3) + c;
            int nextIdx = (b + 1 < nb && nj < deg) ? csr_src[beg + nj] : 0;
            int cnt = min(8, deg - (b << 3));
            int s0 = __shfl(idx, gbase, 64);
            uint4 v0 = hb4[s0 * 8 + c];
            for (int e = 1; e < cnt; ++e) {
                int s1 = __shfl(idx, gbase + e, 64);
                uint4 v1 = hb4[s1 * 8 + c];  // issue before consuming v0
                a0 += lo16(v0.x); a1 += hi16(v0.x);
                a2 += lo16(v0.y); a3 += hi16(v0.y);
                a4 += lo16(v0.z); a5 += hi16(v0.z);
                a6 += lo16(v0.w); a7 += hi16(v0.w);
                v0 = v1;
            }
            a0 += lo16(v0.x); a1 += hi16(v0.x);
            a2 += lo16(v0.y); a3 += hi16(v0.y);
            a4 += lo16(v0.z); a5 += hi16(v0.z);
            a6 += lo16(v0.w); a7 += hi16(v0.w);
            idx = nextIdx;
        }
        if (selff) {
            float4 s0 = selff[(size_t)node * 16 + 2 * c];
            float4 s1 = selff[(size_t)node * 16 + 2 * c + 1];
            a0 += s0.x; a1 += s0.y; a2 += s0.z; a3 += s0.w;
            a4 += s1.x; a5 += s1.y; a6 += s1.z; a7 += s1.w;
        } else {
            uint4 sv = hb4[node * 8 + c];
            a0 += lo16(sv.x); a1 += hi16(sv.x);
            a2 += lo16(sv.y); a3 += hi16(sv.y);
            a4 += lo16(sv.z); a5 += hi16(sv.z);
            a6 += lo16(sv.w); a7 += hi16(sv.w);
        }
        uint4 o;
        o.x = pk(a0, a1); o.y = pk(a2, a3); o.z = pk(a4, a5); o.w = pk(a6, a7);
        *reinterpret_cast<uint4*>(&zl[r * 72 + c * 8]) = o;
    }
    __syncthreads();

    // ---- Phase B: MLP on the 32-row tile ----
    int m = lane & 15;
    int quad = lane >> 4;
    int mt = wv >> 1;  // row half (rows mt*16 + 0..15)
    int nh = wv & 1;   // col half (n-tiles nh*2, nh*2+1)
    int lrow = mt * 16 + m;

    bf16x8 a0 = *reinterpret_cast<const bf16x8*>(&zl[lrow * 72 + quad * 8]);
    bf16x8 a1 = *reinterpret_cast<const bf16x8*>(&zl[lrow * 72 + 32 + quad * 8]);
    const bf16x8* wh1 = reinterpret_cast<const bf16x8*>(wf1);
    const bf16x8* wl1 = reinterpret_cast<const bf16x8*>(wf1 + 4096);
    f32x4 acc[2];
#pragma unroll
    for (int nt2 = 0; nt2 < 2; ++nt2) {
        int n = (nh * 2 + nt2) * 16 + m;
        bf16x8 bh0 = wh1[(0 * 64 + n) * 4 + quad];
        bf16x8 bh1 = wh1[(1 * 64 + n) * 4 + quad];
        bf16x8 bl0 = wl1[(0 * 64 + n) * 4 + quad];
        bf16x8 bl1 = wl1[(1 * 64 + n) * 4 + quad];
        f32x4 c = {0.f, 0.f, 0.f, 0.f};
        c = __builtin_amdgcn_mfma_f32_16x16x32_bf16(a0, bh0, c, 0, 0, 0);
        c = __builtin_amdgcn_mfma_f32_16x16x32_bf16(a1, bh1, c, 0, 0, 0);
        c = __builtin_amdgcn_mfma_f32_16x16x32_bf16(a0, bl0, c, 0, 0, 0);
        c = __builtin_amdgcn_mfma_f32_16x16x32_bf16(a1, bl1, c, 0, 0, 0);
        acc[nt2] = c;
    }
    // h1 = ReLU(acc + b1) -> split bf16 into LDS (C-layout scatter)
#pragma unroll
    for (int nt2 = 0; nt2 < 2; ++nt2) {
        int col = (nh * 2 + nt2) * 16 + m;
        float bb = b1[col];
#pragma unroll
        for (int rr = 0; rr < 4; ++rr) {
            float v = fmaxf(acc[nt2][rr] + bb, 0.f);
            unsigned short hi = f2b(v);
            hlh[(mt * 16 + quad * 4 + rr) * 72 + col] = hi;
            hll[(mt * 16 + quad * 4 + rr) * 72 + col] = f2b(v - b2f(hi));
        }
    }
    __syncthreads();

    // GEMM2: A (hi+lo) from LDS
    bf16x8 ch0 = *reinterpret_cast<const bf16x8*>(&hlh[lrow * 72 + quad * 8]);
    bf16x8 ch1 = *reinterpret_cast<const bf16x8*>(&hlh[lrow * 72 + 32 + quad * 8]);
    bf16x8 cl0 = *reinterpret_cast<const bf16x8*>(&hll[lrow * 72 + quad * 8]);
    bf16x8 cl1 = *reinterpret_cast<const bf16x8*>(&hll[lrow * 72 + 32 + quad * 8]);
    const bf16x8* wh2 = reinterpret_cast<const bf16x8*>(wf2);
    const bf16x8* wl2 = reinterpret_cast<const bf16x8*>(wf2 + 4096);
#pragma unroll
    for (int nt2 = 0; nt2 < 2; ++nt2) {
        int n = (nh * 2 + nt2) * 16 + m;
        bf16x8 bh0 = wh2[(0 * 64 + n) * 4 + quad];
        bf16x8 bh1 = wh2[(1 * 64 + n) * 4 + quad];
        bf16x8 bl0 = wl2[(0 * 64 + n) * 4 + quad];
        bf16x8 bl1 = wl2[(1 * 64 + n) * 4 + quad];
        f32x4 c = {0.f, 0.f, 0.f, 0.f};
        c = __builtin_amdgcn_mfma_f32_16x16x32_bf16(ch0, bh0, c, 0, 0, 0);
        c = __builtin_amdgcn_mfma_f32_16x16x32_bf16(ch1, bh1, c, 0, 0, 0);
        c = __builtin_amdgcn_mfma_f32_16x16x32_bf16(ch0, bl0, c, 0, 0, 0);
        c = __builtin_amdgcn_mfma_f32_16x16x32_bf16(ch1, bl1, c, 0, 0, 0);
        c = __builtin_amdgcn_mfma_f32_16x16x32_bf16(cl0, bh0, c, 0, 0, 0);
        c = __builtin_amdgcn_mfma_f32_16x16x32_bf16(cl1, bh1, c, 0, 0, 0);
        acc[nt2] = c;
    }
    __syncthreads();  // all GEMM2 LDS reads done; hlh/hll reusable

    if (pool_mode) {
        // fused global_add_pool + FC
        float psum[4] = {0.f, 0.f, 0.f, 0.f};
#pragma unroll
        for (int nt2 = 0; nt2 < 2; ++nt2) {
            int col = (nh * 2 + nt2) * 16 + m;
            float fw = fcw[col];
            float bb = b2[col];
#pragma unroll
            for (int rr = 0; rr < 4; ++rr) psum[rr] += (acc[nt2][rr] + bb) * fw;
        }
#pragma unroll
        for (int rr = 0; rr < 4; ++rr)
#pragma unroll
            for (int off = 8; off > 0; off >>= 1)
                psum[rr] += __shfl_down(psum[rr], off, 64);
        float* gsum = reinterpret_cast<float*>(hlh);
        gsum[tid] = 0.f;  // tid 0..255 == graph ids
        __syncthreads();
        if (m == 0) {
#pragma unroll
            for (int rr = 0; rr < 4; ++rr) {
                int row = base + mt * 16 + quad * 4 + rr;
                atomicAdd(&gsum[batch[row]], psum[rr]);
            }
        }
        __syncthreads();
        float v = gsum[tid];
        if (v != 0.f) unsafeAtomicAdd(&outp[tid], v);
        return;
    }

    // epilogue: bias (+relu) -> LDS bf16, then coalesced stores
#pragma unroll
    for (int nt2 = 0; nt2 < 2; ++nt2) {
        int col = (nh * 2 + nt2) * 16 + m;
        float bb = b2[col];
#pragma unroll
        for (int rr = 0; rr < 4; ++rr) {
            float v = acc[nt2][rr] + bb;
            if (relu_out) v = fmaxf(v, 0.f);
            hlh[(mt * 16 + quad * 4 + rr) * 72 + col] = f2b(v);
        }
    }
    __syncthreads();
    {
        int row = tid >> 3;  // 0..31
        int ch = tid & 7;
        uint4 v = *reinterpret_cast<const uint4*>(&hlh[row * 72 + ch * 8]);
        *reinterpret_cast<uint4*>(houtb + (size_t)(base + row) * 64 + ch * 8) = v;
    }
}

extern "C" void kernel_launch(void* const* d_in, const int* in_sizes, int n_in,
                              void* d_out, int out_size, void* d_ws, size_t ws_size,
                              hipStream_t stream) {
    const float* x = (const float*)d_in[0];
    const int* ei = (const int*)d_in[1];     // [2, E] flat
    const int* batch = (const int*)d_in[2];  // [N], sorted
    const float* w[3][4];
    for (int l = 0; l < 3; ++l)
        for (int i = 0; i < 4; ++i) w[l][i] = (const float*)d_in[3 + l * 4 + i];
    const float* fcw = (const float*)d_in[15];
    const float* fcb = (const float*)d_in[16];
    float* out = (float*)d_out;

    // workspace layout (~43 MB), every region 256 B aligned
    char* wsb = (char*)d_ws;
    size_t o = 0;
    auto carve = [&](size_t bytes) {
        char* p = wsb + o;
        o += (bytes + 255) & ~(size_t)255;
        return p;
    };
    int* pairs = (int*)carve((size_t)NEB * EPB * 4);       // 6.4 MB
    int* ocnt = (int*)carve((size_t)NEB * NBKT * 4);       // 0.6 MB
    int* csr = (int*)carve((size_t)NBKT * CAP * 4);        // 9.6 MB
    int* rowptr = (int*)carve((size_t)NN * 4);
    int* degs = (int*)carve((size_t)NN * 4);
    unsigned short* H0 = (unsigned short*)carve((size_t)NN * DD * 2);  // 12.8 MB
    unsigned short* H1 = (unsigned short*)carve((size_t)NN * DD * 2);  // 12.8 MB
    unsigned short* wf = (unsigned short*)carve(6 * 8192 * 2);

    // D1: pscat (no-atomic count matrix) + wconv + out-init + xconv
    build1_k<<<NEB + 7 + XCB, 256, 0, stream>>>(ei, pairs, ocnt, x, H0, w[0][0],
                                                w[0][2], w[1][0], w[1][2],
                                                w[2][0], w[2][2], wf, fcb, out);
    // D2: bucket gather + per-node counting sort -> csr/rowptr/degs
    build2_k<<<NBKT, 256, 0, stream>>>(pairs, ocnt, rowptr, degs, csr);

    dim3 lgrid(NN / 32);
    // D3 L0: read H0(=xb)+x, write H1
    gin_k<<<lgrid, 256, 0, stream>>>((const uint4*)H0, (const float4*)x, rowptr,
                                     degs, csr, wf + 0 * 8192, w[0][1],
                                     wf + 1 * 8192, w[0][3], H1, 1, 0, nullptr,
                                     nullptr, nullptr);
    // D4 L1: read H1, write H0
    gin_k<<<lgrid, 256, 0, stream>>>((const uint4*)H1, nullptr, rowptr, degs,
                                     csr, wf + 2 * 8192, w[1][1], wf + 3 * 8192,
                                     w[1][3], H0, 1, 0, nullptr, nullptr,
                                     nullptr);
    // D5 L2: read H0, fused pool + FC
    gin_k<<<lgrid, 256, 0, stream>>>((const uint4*)H0, nullptr, rowptr, degs,
                                     csr, wf + 4 * 8192, w[2][1], wf + 5 * 8192,
                                     w[2][3], nullptr, 0, 1, batch, fcw, out);
}